// Round 3
// baseline (753.330 us; speedup 1.0000x reference)
//
#include <hip/hip_runtime.h>
#include <hip/hip_bf16.h>
#include <cstdint>

#define S_LEN 2048
#define B_SZ  32
#define H_DIM 1024
#define U_DIM 1024

using short8  = __attribute__((ext_vector_type(8))) short;
using ushort8 = __attribute__((ext_vector_type(8))) unsigned short;
using floatx4 = __attribute__((ext_vector_type(4))) float;

typedef __attribute__((address_space(3))) void lds_void;
typedef const __attribute__((address_space(1))) void glb_void;
#define GLD16(g, s) __builtin_amdgcn_global_load_lds((glb_void*)(g), (lds_void*)(s), 16, 0, 0)

__device__ __forceinline__ unsigned short f32_to_bf16_rne(float f) {
    unsigned int u = __float_as_uint(f);
    unsigned int r = (u + 0x7fffu + ((u >> 16) & 1u)) >> 16;
    return (unsigned short)r;
}

// fast tanh: t = 1 - 2/(e^{2x}+1); exact at +-inf via rcp(inf)=0 / rcp(1)=1
__device__ __forceinline__ float fast_tanh(float x) {
    float e = __expf(2.f * x);
    return 1.f - 2.f * __builtin_amdgcn_rcpf(e + 1.f);
}

// ---------------- W1 [H][U] f32 -> W1t [U][H] bf16 ----------------
__global__ void transpose_cast_w1(const float* __restrict__ W1,
                                  unsigned short* __restrict__ W1t) {
    __shared__ float tile[32][33];
    const int tx = threadIdx.x, ty = threadIdx.y;      // 32 x 8
    const int u0 = blockIdx.x * 32, h0 = blockIdx.y * 32;
#pragma unroll
    for (int i = 0; i < 4; ++i)
        tile[ty * 4 + i][tx] = W1[(size_t)(h0 + ty * 4 + i) * U_DIM + u0 + tx];
    __syncthreads();
#pragma unroll
    for (int i = 0; i < 4; ++i)
        W1t[(size_t)(u0 + ty * 4 + i) * H_DIM + h0 + tx] =
            f32_to_bf16_rne(tile[tx][ty * 4 + i]);
}

// ---------------- query v2: split-H partial sums + atomics ----------------
__global__ __launch_bounds__(128)
void query_kernel_v2(const float* __restrict__ hidden_t,
                     const float* __restrict__ W2,
                     const float* __restrict__ b1,
                     const float* __restrict__ b2,
                     float* __restrict__ query) {
    const int b  = blockIdx.z;
    const int hc = blockIdx.y;                 // 8 chunks of 128 h
    const int u  = blockIdx.x * 128 + threadIdx.x;
    const float* ht = hidden_t + b * H_DIM + hc * 128;
    const float* w  = W2 + (size_t)hc * 128 * U_DIM + u;
    float acc = (hc == 0) ? (b1[u] + b2[u]) : 0.f;
#pragma unroll 8
    for (int h = 0; h < 128; ++h)
        acc = fmaf(ht[h], w[(size_t)h * U_DIM], acc);
    atomicAdd(&query[b * U_DIM + u], acc);
}

// ---------------- v7: 128x128 tile, fused f32->bf16 A-cast (reg-staged),
// 64 KiB LDS double-buffer -> 2 blocks/CU (cross-block TLP fills barrier
// bubbles that bound v5/v6), ONE barrier per K-tile, counted vmcnt never
// drains. Per-wave vm queue at every wait is exactly [A:8, B:4].
//   tile t: STAGE_B(t+1)->nc; vmcnt(4) A(t+1) regs ready; pack+ds_write
//           A(t+1)->nc; issue A(t+2) loads; {reads, lgkmcnt(0), 16 MFMA} x2
//           on buf c; vmcnt(8) retires B(t+1) (A(t+2) stays in flight);
//           s_barrier.
// Bank check (quarter-wave, 16 lanes): XOR chunk swizzle gives 2-way on both
// ds_read_b128 and ds_write_b128 -> free (m136); matches measured 0 conflicts.
__global__ __launch_bounds__(256, 2)
void keys_score_v7(const float* __restrict__ hiddens,
                   const unsigned short* __restrict__ W1t,
                   const float* __restrict__ query,
                   const float* __restrict__ V,
                   float* __restrict__ scores) {
    __shared__ unsigned short As[2][128 * 64];   // 16 KiB per buffer
    __shared__ unsigned short Bs[2][128 * 64];   // total 64 KiB

    const int tid = threadIdx.x;
    const int w = tid >> 6, l = tid & 63;
    const int q = l >> 4, r = l & 15, r7 = l & 7;
    const int wr = w >> 1, wc = w & 1;           // 2M x 2N waves, 64x64 each

    // grid 4096 = 512 m-tiles x 8 n-tiles. Bijective XCD swizzle (4096%8==0),
    // n-fastest within an XCD: 8 consecutive blocks share one A panel (L2 hit
    // x8), and the whole W1t (2 MB) is L2-resident per XCD.
    const int bid = blockIdx.x;
    const int wg  = (bid & 7) * 512 + (bid >> 3);
    const int m0 = (wg >> 3) << 7;
    const int n0 = (wg & 7) << 7;

    // ---- A staging (fused cast): thread -> row=tid>>1, half=tid&1 (32 cols)
    const int arow  = tid >> 1;
    const int ahalf = tid & 1;
    const int ar7   = arow & 7;
    const float* gAf = hiddens + (size_t)(m0 + arow) * H_DIM + ahalf * 32;
    const int awrow = arow << 6;                 // LDS row base (elems)

    // ---- B staging (GLD16, pre-swizzled global source; linear LDS dest)
    const int srow = l >> 3;
    const int gch  = ((l & 7) ^ srow) << 3;
    const unsigned short* gB = W1t + ((size_t)(n0 + w * 32 + srow) << 10) + gch;
    const int bwbase = (w * 32) << 6;            // wave-uniform

    floatx4 acc[4][4];
#pragma unroll
    for (int mt = 0; mt < 4; ++mt)
#pragma unroll
        for (int nt = 0; nt < 4; ++nt)
            acc[mt][nt] = (floatx4){0.f, 0.f, 0.f, 0.f};

#define LOADA(t, ra)                                                          \
    {                                                                         \
        const float* _g = gAf + ((t) << 6);                                   \
        _Pragma("unroll")                                                     \
        for (int _j = 0; _j < 8; ++_j)                                        \
            ra[_j] = *(const float4*)(_g + _j * 4);                           \
    }
    // pack 2 float4 -> 8 bf16, write to XOR-swizzled chunk of buffer d
#define WRITEA(d, ra)                                                         \
    {                                                                         \
        _Pragma("unroll")                                                     \
        for (int _c = 0; _c < 4; ++_c) {                                      \
            ushort8 _pk;                                                      \
            _pk[0] = f32_to_bf16_rne(ra[2 * _c].x);                           \
            _pk[1] = f32_to_bf16_rne(ra[2 * _c].y);                           \
            _pk[2] = f32_to_bf16_rne(ra[2 * _c].z);                           \
            _pk[3] = f32_to_bf16_rne(ra[2 * _c].w);                           \
            _pk[4] = f32_to_bf16_rne(ra[2 * _c + 1].x);                       \
            _pk[5] = f32_to_bf16_rne(ra[2 * _c + 1].y);                       \
            _pk[6] = f32_to_bf16_rne(ra[2 * _c + 1].z);                       \
            _pk[7] = f32_to_bf16_rne(ra[2 * _c + 1].w);                       \
            *(ushort8*)&As[d][awrow + (((ahalf * 4 + _c) ^ ar7) << 3)] = _pk; \
        }                                                                     \
    }
#define STAGE_B(t, d)                                                         \
    {                                                                         \
        const unsigned short* _g = gB + ((size_t)(t) << 6);                   \
        _Pragma("unroll")                                                     \
        for (int _i = 0; _i < 4; ++_i)                                        \
            GLD16(_g + ((size_t)(_i * 8) << 10), &Bs[d][bwbase + _i * 512]);  \
    }

    float4 raP[8], ra[8];

    // ---- prologue: queue order [A0:8][B0:4][A1:8] ----
    LOADA(0, raP);
    STAGE_B(0, 0);
    LOADA(1, ra);
    asm volatile("s_waitcnt vmcnt(12)" ::: "memory");   // A0 ready
    __builtin_amdgcn_sched_barrier(0);
    WRITEA(0, raP);
    asm volatile("s_waitcnt vmcnt(8)" ::: "memory");    // B0 landed; A1 in flight
    asm volatile("s_waitcnt lgkmcnt(0)" ::: "memory");  // my A0 writes done
    __builtin_amdgcn_s_barrier();

    const int ch0 = (q ^ r7) << 3;               // kk=0 chunk offset (elems)
    const int ch1 = ((4 | q) ^ r7) << 3;         // kk=1 chunk offset

    for (int kt = 0; kt < 16; ++kt) {
        const int c = kt & 1, nc = c ^ 1;
        const int tB = (kt + 1 < 16) ? kt + 1 : 15;   // clamps keep vm counts uniform
        const int tA = (kt + 2 < 16) ? kt + 2 : 15;

        // top: stage B(t+1); A(t+1) regs arrive; write A(t+1); launch A(t+2)
        STAGE_B(tB, nc);                              // queue: A(t+1):8, B(t+1):4
        asm volatile("s_waitcnt vmcnt(4)" ::: "memory");   // A(t+1) ready
        __builtin_amdgcn_sched_barrier(0);
        WRITEA(nc, ra);
        LOADA(tA, ra);                                // queue: B(t+1):4, A(t+2):8

        // phase kk0 on buffer c
        short8 af[4], bf[4];
#pragma unroll
        for (int mt = 0; mt < 4; ++mt)
            af[mt] = *(const short8*)&As[c][((wr * 64 + mt * 16 + r) << 6) + ch0];
#pragma unroll
        for (int nt = 0; nt < 4; ++nt)
            bf[nt] = *(const short8*)&Bs[c][((wc * 64 + nt * 16 + r) << 6) + ch0];
        asm volatile("s_waitcnt lgkmcnt(0)" ::: "memory");
        __builtin_amdgcn_sched_barrier(0);
        __builtin_amdgcn_s_setprio(1);
#pragma unroll
        for (int mt = 0; mt < 4; ++mt)
#pragma unroll
            for (int nt = 0; nt < 4; ++nt)
                acc[mt][nt] = __builtin_amdgcn_mfma_f32_16x16x32_bf16(
                    af[mt], bf[nt], acc[mt][nt], 0, 0, 0);
        __builtin_amdgcn_s_setprio(0);

        // phase kk1 on buffer c
#pragma unroll
        for (int mt = 0; mt < 4; ++mt)
            af[mt] = *(const short8*)&As[c][((wr * 64 + mt * 16 + r) << 6) + ch1];
#pragma unroll
        for (int nt = 0; nt < 4; ++nt)
            bf[nt] = *(const short8*)&Bs[c][((wc * 64 + nt * 16 + r) << 6) + ch1];
        asm volatile("s_waitcnt lgkmcnt(0)" ::: "memory");
        __builtin_amdgcn_sched_barrier(0);
        __builtin_amdgcn_s_setprio(1);
#pragma unroll
        for (int mt = 0; mt < 4; ++mt)
#pragma unroll
            for (int nt = 0; nt < 4; ++nt)
                acc[mt][nt] = __builtin_amdgcn_mfma_f32_16x16x32_bf16(
                    af[mt], bf[nt], acc[mt][nt], 0, 0, 0);
        __builtin_amdgcn_s_setprio(0);

        // close tile: B(t+1) must be in LDS for everyone; A(t+2) stays in flight
        asm volatile("s_waitcnt vmcnt(8)" ::: "memory");
        __builtin_amdgcn_s_barrier();
    }
#undef LOADA
#undef WRITEA
#undef STAGE_B

    // ---- epilogue: tanh(keys+query)*V, 16-lane reduce over cols, atomic ----
    const float* qrow = query + (m0 >> 11) * U_DIM;
#pragma unroll
    for (int mt = 0; mt < 4; ++mt) {
#pragma unroll
        for (int reg = 0; reg < 4; ++reg) {
            float sum = 0.f;
#pragma unroll
            for (int nt = 0; nt < 4; ++nt) {
                const int cc = n0 + wc * 64 + nt * 16 + r;
                float t = fast_tanh(acc[mt][nt][reg] + qrow[cc]);
                sum = fmaf(t, V[cc], sum);
            }
            sum += __shfl_xor(sum, 1);
            sum += __shfl_xor(sum, 2);
            sum += __shfl_xor(sum, 4);
            sum += __shfl_xor(sum, 8);
            if (r == 0)
                atomicAdd(&scores[m0 + wr * 64 + mt * 16 + q * 4 + reg], sum);
        }
    }
}

// ---------------- softmax stats: per-batch max and 1/sum ----------------
__global__ __launch_bounds__(256)
void softmax_stats_kernel(const float* __restrict__ scores,
                          float2* __restrict__ stats) {
    const int b = blockIdx.x, tid = threadIdx.x;
    const int wave = tid >> 6, lane = tid & 63;
    const float* src = scores + b * S_LEN;
    float v[8];
    float m = -1e30f;
#pragma unroll
    for (int i = 0; i < 8; ++i) { v[i] = src[tid + i * 256]; m = fmaxf(m, v[i]); }
#pragma unroll
    for (int off = 32; off >= 1; off >>= 1) m = fmaxf(m, __shfl_xor(m, off));
    __shared__ float red[4];
    if (lane == 0) red[wave] = m;
    __syncthreads();
    m = fmaxf(fmaxf(red[0], red[1]), fmaxf(red[2], red[3]));
    __syncthreads();
    float s = 0.f;
#pragma unroll
    for (int i = 0; i < 8; ++i) s += __expf(v[i] - m);
#pragma unroll
    for (int off = 32; off >= 1; off >>= 1) s += __shfl_xor(s, off);
    if (lane == 0) red[wave] = s;
    __syncthreads();
    if (tid == 0) {
        s = red[0] + red[1] + red[2] + red[3];
        stats[b] = make_float2(m, 1.f / s);
    }
}

// ---------------- context partial: weights + partial sums, NO atomics ----------------
__global__ __launch_bounds__(256)
void context_partial_kernel(const float* __restrict__ scores,
                            const float2* __restrict__ stats,
                            const float* __restrict__ hiddens,
                            float* __restrict__ out_w,
                            float* __restrict__ partial) {
    const int b = blockIdx.y, sc = blockIdx.x;  // 16 chunks of 128 s
    const int tid = threadIdx.x;
    __shared__ float wsm[128];

    const float2 st = stats[b];
    if (tid < 128) {
        const int s = sc * 128 + tid;
        const float w = __expf(scores[b * S_LEN + s] - st.x) * st.y;
        wsm[tid] = w;
        out_w[b * S_LEN + s] = w;
    }
    __syncthreads();

    const float* hbase = hiddens + ((size_t)b * S_LEN + sc * 128) * H_DIM + tid * 4;
    float4 acc = make_float4(0.f, 0.f, 0.f, 0.f);
#pragma unroll 4
    for (int s = 0; s < 128; ++s) {
        const float w = wsm[s];
        float4 hv = *(const float4*)(hbase + (size_t)s * H_DIM);
        acc.x = fmaf(w, hv.x, acc.x);
        acc.y = fmaf(w, hv.y, acc.y);
        acc.z = fmaf(w, hv.z, acc.z);
        acc.w = fmaf(w, hv.w, acc.w);
    }
    *(float4*)(partial + ((size_t)(b * 16 + sc) << 10) + tid * 4) = acc;
}

// ---------------- context reduce: sum 16 partials per batch ----------------
__global__ __launch_bounds__(256)
void context_reduce_kernel(const float* __restrict__ partial,
                           float* __restrict__ out_ctx) {
    const int b = blockIdx.x, tid = threadIdx.x;
    float4 acc = make_float4(0.f, 0.f, 0.f, 0.f);
#pragma unroll
    for (int sc = 0; sc < 16; ++sc) {
        float4 p = *(const float4*)(partial + ((size_t)(b * 16 + sc) << 10) + tid * 4);
        acc.x += p.x; acc.y += p.y; acc.z += p.z; acc.w += p.w;
    }
    *(float4*)(out_ctx + b * H_DIM + tid * 4) = acc;
}

extern "C" void kernel_launch(void* const* d_in, const int* in_sizes, int n_in,
                              void* d_out, int out_size, void* d_ws, size_t ws_size,
                              hipStream_t stream) {
    const float* hidden_t = (const float*)d_in[0];
    const float* hiddens  = (const float*)d_in[1];
    const float* W1       = (const float*)d_in[2];
    const float* b1       = (const float*)d_in[3];
    const float* W2       = (const float*)d_in[4];
    const float* b2       = (const float*)d_in[5];
    const float* V        = (const float*)d_in[6];
    // d_in[7] = bV: softmax-invariant, unused.

    float* out_ctx = (float*)d_out;                  // [32,1024]
    float* out_w   = (float*)d_out + B_SZ * H_DIM;   // [32,2048,1]

    char* ws = (char*)d_ws;
    unsigned short* W1t = (unsigned short*)ws;                        // 2 MiB @ 0
    float*  query   = (float*)(ws + (2u << 20));                      // 128 KiB
    float*  scores  = query + B_SZ * U_DIM;                           // 256 KiB
    float2* stats   = (float2*)(scores + B_SZ * S_LEN);               // 256 B
    float*  partial = (float*)(ws + (3u << 20));                      // 2 MiB @ 3 MiB

    hipMemsetAsync(query,  0, (size_t)B_SZ * U_DIM * sizeof(float), stream);
    hipMemsetAsync(scores, 0, (size_t)B_SZ * S_LEN * sizeof(float), stream);

    transpose_cast_w1<<<dim3(32, 32), dim3(32, 8), 0, stream>>>(W1, W1t);
    query_kernel_v2<<<dim3(8, 8, B_SZ), 128, 0, stream>>>(hidden_t, W2, b1, b2, query);

    // 512 m-tiles x 8 n-tiles = 4096 blocks (XCD swizzle assumes 4096)
    keys_score_v7<<<4096, 256, 0, stream>>>(hiddens, W1t, query, V, scores);

    softmax_stats_kernel<<<B_SZ, 256, 0, stream>>>(scores, stats);
    context_partial_kernel<<<dim3(16, B_SZ), 256, 0, stream>>>(
        scores, stats, hiddens, out_w, partial);
    context_reduce_kernel<<<B_SZ, 256, 0, stream>>>(partial, out_ctx);
}